// Round 1
// baseline (1153.035 us; speedup 1.0000x reference)
//
#include <hip/hip_runtime.h>

namespace {

constexpr int NB = 8, NP = 8192, NC = 91;
constexpr int KTOP = 1000, NDET = 100;
constexpr int CAP = 65536;           // per-image candidate capacity (~4x expected 16k)
constexpr int NBUCK = 4096, SORTN = 4096;
constexpr float SCORE_T = 0.05f;
constexpr float MIN_SZ = 0.01f;
constexpr float NMS_T = 0.5f;
constexpr float CLIPV = 4.135166556742356f;  // log(1000/16)
constexpr float NEGV = -1e9f;

__device__ __forceinline__ void decode_box(const float4& pr, const float4& rel,
                                           float Wf, float Hf,
                                           float& x1, float& y1, float& x2, float& y2) {
  float w = pr.z - pr.x, h = pr.w - pr.y;
  float cx = pr.x + 0.5f * w, cy = pr.y + 0.5f * h;
  float dx = rel.x / 10.0f, dy = rel.y / 10.0f;
  float dw = fminf(rel.z / 5.0f, CLIPV), dh = fminf(rel.w / 5.0f, CLIPV);
  float pcx = dx * w + cx, pcy = dy * h + cy;
  float pw = expf(dw) * w, ph = expf(dh) * h;
  x1 = fminf(fmaxf(pcx - 0.5f * pw, 0.0f), Wf);
  y1 = fminf(fmaxf(pcy - 0.5f * ph, 0.0f), Hf);
  x2 = fminf(fmaxf(pcx + 0.5f * pw, 0.0f), Wf);
  y2 = fminf(fmaxf(pcy + 0.5f * ph, 0.0f), Hf);
}

__global__ __launch_bounds__(64) void k_zero(int* cand_cnt) {
  if (threadIdx.x < NB) cand_cnt[threadIdx.x] = 0;
}

// One wave (64 lanes) per proposal: softmax over 91 classes, decode only
// score-passing candidates, ballot-aggregated append.
__global__ __launch_bounds__(256) void k_candidates(
    const float* __restrict__ logits, const float* __restrict__ boxreg,
    const float* __restrict__ props, const int* __restrict__ hw,
    float* __restrict__ cand_score, int* __restrict__ cand_idx,
    int* __restrict__ cand_cnt) {
  int gw = (int)((blockIdx.x * blockDim.x + threadIdx.x) >> 6);
  int lane = threadIdx.x & 63;
  if (gw >= NB * NP) return;
  int b = gw / NP, p = gw % NP;
  float Hf = (float)hw[0], Wf = (float)hw[1];
  const float* lrow = logits + (size_t)gw * NC;
  float z0 = (lane < NC) ? lrow[lane] : -3.0e38f;
  float z1 = (lane + 64 < NC) ? lrow[lane + 64] : -3.0e38f;
  float mx = fmaxf(z0, z1);
#pragma unroll
  for (int o = 32; o > 0; o >>= 1) mx = fmaxf(mx, __shfl_xor(mx, o, 64));
  float e0 = (lane < NC) ? expf(z0 - mx) : 0.0f;
  float e1 = (lane + 64 < NC) ? expf(z1 - mx) : 0.0f;
  float sm = e0 + e1;
#pragma unroll
  for (int o = 32; o > 0; o >>= 1) sm += __shfl_xor(sm, o, 64);
  float4 pr = reinterpret_cast<const float4*>(props)[gw];
  const float4* relrow = reinterpret_cast<const float4*>(boxreg + (size_t)gw * 4 * NC);

#pragma unroll
  for (int pass = 0; pass < 2; ++pass) {
    int c = lane + pass * 64;
    float e = pass ? e1 : e0;
    float sc = e / sm;
    bool ok = (c >= 1) && (c < NC) && (sc > SCORE_T);
    if (ok) {
      float4 rel = relrow[c];
      float x1, y1, x2, y2;
      decode_box(pr, rel, Wf, Hf, x1, y1, x2, y2);
      ok = ((x2 - x1) >= MIN_SZ) && ((y2 - y1) >= MIN_SZ);
    }
    unsigned long long mk = __ballot(ok);
    if (mk) {
      int leader = __builtin_ctzll(mk);
      int base = 0;
      if (lane == leader) base = atomicAdd(&cand_cnt[b], __popcll(mk));
      base = __shfl(base, leader, 64);
      if (ok) {
        int pos = base + __popcll(mk & ((1ull << lane) - 1ull));
        if (pos < CAP) {
          cand_score[(size_t)b * CAP + pos] = sc;
          cand_idx[(size_t)b * CAP + pos] = p * (NC - 1) + (c - 1);
        }
      }
    }
  }
}

// Per-image exact top-1000: histogram radix-select on float bits, compact,
// bitonic sort by (score desc, idx asc).
__global__ __launch_bounds__(1024) void k_select(
    const float* __restrict__ cand_score, const int* __restrict__ cand_idx,
    const int* __restrict__ cand_cnt,
    float* __restrict__ topk_score, int* __restrict__ topk_idx) {
  __shared__ int hist[NBUCK];
  __shared__ unsigned long long keys[SORTN];
  __shared__ int ncomp;
  __shared__ int sbound;
  int b = blockIdx.x, tid = threadIdx.x;
  int cnt = min(cand_cnt[b], CAP);
  for (int i = tid; i < NBUCK; i += 1024) hist[i] = 0;
  if (tid == 0) { ncomp = 0; sbound = 0; }
  __syncthreads();
  const float* cs = cand_score + (size_t)b * CAP;
  const int* ci = cand_idx + (size_t)b * CAP;
  for (int i = tid; i < cnt; i += 1024) {
    unsigned bits = __float_as_uint(cs[i]);
    int bk = min((int)((bits - 0x3D000000u) >> 14), NBUCK - 1);
    atomicAdd(&hist[bk], 1);
  }
  __syncthreads();
  // inclusive suffix scan of hist (count of candidates in buckets >= i)
  for (int d = 1; d < NBUCK; d <<= 1) {
    int v[NBUCK / 1024];
#pragma unroll
    for (int k = 0; k < NBUCK / 1024; ++k) {
      int i = tid + k * 1024;
      v[k] = hist[i] + ((i + d < NBUCK) ? hist[i + d] : 0);
    }
    __syncthreads();
#pragma unroll
    for (int k = 0; k < NBUCK / 1024; ++k) hist[tid + k * 1024] = v[k];
    __syncthreads();
  }
#pragma unroll
  for (int k = 0; k < NBUCK / 1024; ++k) {
    int i = tid + k * 1024;
    if (hist[i] >= KTOP && (i == NBUCK - 1 || hist[i + 1] < KTOP)) sbound = i;
  }
  __syncthreads();
  int bd = sbound;
  for (int i = tid; i < cnt; i += 1024) {
    unsigned bits = __float_as_uint(cs[i]);
    int bk = min((int)((bits - 0x3D000000u) >> 14), NBUCK - 1);
    if (bk >= bd) {
      int pos = atomicAdd(&ncomp, 1);
      if (pos < SORTN)
        keys[pos] = ((unsigned long long)bits << 32) | (unsigned)(~(unsigned)ci[i]);
    }
  }
  __syncthreads();
  int total = min(ncomp, SORTN);
  for (int i = tid; i < SORTN; i += 1024)
    if (i >= total) keys[i] = 0ull;
  __syncthreads();
  // bitonic sort, descending by 64-bit key
  for (int k = 2; k <= SORTN; k <<= 1) {
    for (int j = k >> 1; j > 0; j >>= 1) {
      for (int t = tid; t < SORTN; t += 1024) {
        int ixj = t ^ j;
        if (ixj > t) {
          unsigned long long a = keys[t], c2 = keys[ixj];
          bool up = ((t & k) == 0);
          bool sw = up ? (a < c2) : (a > c2);
          if (sw) { keys[t] = c2; keys[ixj] = a; }
        }
      }
      __syncthreads();
    }
  }
  int valid_n = min(total, KTOP);
  if (tid < KTOP) {
    if (tid < valid_n) {
      unsigned long long key = keys[tid];
      topk_score[b * KTOP + tid] = __uint_as_float((unsigned)(key >> 32));
      topk_idx[b * KTOP + tid] = (int)(~(unsigned)key);
    } else {
      topk_score[b * KTOP + tid] = NEGV;
      topk_idx[b * KTOP + tid] = -1;
    }
  }
}

__global__ __launch_bounds__(256) void k_decode(
    const float* __restrict__ boxreg, const float* __restrict__ props,
    const int* __restrict__ hw, const int* __restrict__ topk_idx,
    float* __restrict__ det_box, int* __restrict__ det_label,
    int* __restrict__ det_valid) {
  int g = blockIdx.x * 256 + threadIdx.x;
  if (g >= NB * KTOP) return;
  int b = g / KTOP;
  int fidx = topk_idx[g];
  if (fidx < 0) {
    det_box[(size_t)g * 4 + 0] = 0.0f;
    det_box[(size_t)g * 4 + 1] = 0.0f;
    det_box[(size_t)g * 4 + 2] = 0.0f;
    det_box[(size_t)g * 4 + 3] = 0.0f;
    det_label[g] = 0;
    det_valid[g] = 0;
    return;
  }
  int p = fidx / (NC - 1), c = fidx % (NC - 1) + 1;
  float Hf = (float)hw[0], Wf = (float)hw[1];
  float4 pr = reinterpret_cast<const float4*>(props)[b * NP + p];
  float4 rel =
      reinterpret_cast<const float4*>(boxreg + (size_t)(b * NP + p) * 4 * NC)[c];
  float x1, y1, x2, y2;
  decode_box(pr, rel, Wf, Hf, x1, y1, x2, y2);
  det_box[(size_t)g * 4 + 0] = x1;
  det_box[(size_t)g * 4 + 1] = y1;
  det_box[(size_t)g * 4 + 2] = x2;
  det_box[(size_t)g * 4 + 3] = y2;
  det_label[g] = c;
  det_valid[g] = 1;
}

// Suppression bit-matrix: bit t of word w of row (b,i) = [j=w*64+t > i, same
// label, IoU > 0.5].  (Class offsets in the reference make cross-class IoU
// exactly 0 since offset_scale=1334 > max coord 1333, so label equality is an
// exact replacement.)
__global__ __launch_bounds__(256) void k_mask(
    const float* __restrict__ det_box, const int* __restrict__ det_label,
    unsigned long long* __restrict__ maskmat) {
  int g = blockIdx.x * 256 + threadIdx.x;
  if (g >= NB * KTOP * 16) return;
  int w = g & 15;
  int i = (g >> 4) % KTOP;
  int b = (g >> 4) / KTOP;
  const float4* bb = reinterpret_cast<const float4*>(det_box) + (size_t)b * KTOP;
  const int* ll = det_label + b * KTOP;
  float4 bi = bb[i];
  int li = ll[i];
  float areai = (bi.z - bi.x) * (bi.w - bi.y);
  unsigned long long bits = 0;
  int j0 = w * 64;
  for (int t = 0; t < 64; ++t) {
    int j = j0 + t;
    if (j > i && j < KTOP && ll[j] == li) {
      float4 bj = bb[j];
      float areaj = (bj.z - bj.x) * (bj.w - bj.y);
      float ltx = fmaxf(bi.x, bj.x), lty = fmaxf(bi.y, bj.y);
      float rbx = fminf(bi.z, bj.z), rby = fminf(bi.w, bj.w);
      float iw = fmaxf(rbx - ltx, 0.0f), ih = fmaxf(rby - lty, 0.0f);
      float inter = iw * ih;
      float iou = inter / (areai + areaj - inter + 1e-9f);
      if (iou > NMS_T) bits |= (1ull << t);
    }
  }
  maskmat[(size_t)(b * KTOP + i) * 16 + w] = bits;
}

// Serial greedy NMS scan: 1 wave per image; lanes 0..15 hold the 1000-bit
// suppression state as uint64 words; 8-row double-buffered register prefetch.
__global__ __launch_bounds__(64) void k_greedy(
    const unsigned long long* __restrict__ maskmat,
    const int* __restrict__ det_valid, int* __restrict__ keep) {
  int b = blockIdx.x;
  int lane = threadIdx.x;
  unsigned long long validw = 0;
#pragma unroll
  for (int w = 0; w < 16; ++w) {
    int j = w * 64 + lane;
    int f = (j < KTOP) ? det_valid[b * KTOP + j] : 0;
    unsigned long long m = __ballot(f != 0);
    if (lane == w) validw = m;
  }
  unsigned long long supp = 0;
  const unsigned long long* mrow = maskmat + (size_t)b * KTOP * 16;
  int wl = (lane < 16) ? lane : 0;
  unsigned long long cur[8], nxt[8];
#pragma unroll
  for (int r = 0; r < 8; ++r) cur[r] = mrow[(size_t)r * 16 + wl];
  for (int t0 = 0; t0 < KTOP; t0 += 8) {
    int nt0 = t0 + 8;
#pragma unroll
    for (int r = 0; r < 8; ++r) {
      int row = nt0 + r;
      nxt[r] = (row < KTOP) ? mrow[(size_t)row * 16 + wl] : 0ull;
    }
#pragma unroll
    for (int r = 0; r < 8; ++r) {
      int i = t0 + r;
      if (i < KTOP) {
        int w = i >> 6, bit = i & 63;
        unsigned long long sw = ((unsigned long long)(unsigned)__shfl((int)(supp >> 32), w, 64) << 32) |
                                (unsigned)__shfl((int)(supp & 0xffffffffull), w, 64);
        unsigned long long vw = ((unsigned long long)(unsigned)__shfl((int)(validw >> 32), w, 64) << 32) |
                                (unsigned)__shfl((int)(validw & 0xffffffffull), w, 64);
        bool active = (((sw >> bit) & 1ull) == 0ull) && (((vw >> bit) & 1ull) != 0ull);
        if (active) supp |= cur[r];
      }
    }
#pragma unroll
    for (int r = 0; r < 8; ++r) cur[r] = nxt[r];
  }
  if (lane < 16) {
    for (int bit = 0; bit < 64; ++bit) {
      int i = lane * 64 + bit;
      if (i < KTOP)
        keep[b * KTOP + i] =
            ((((supp >> bit) & 1ull) == 0ull) && (((validw >> bit) & 1ull) != 0ull)) ? 1 : 0;
    }
  }
}

// First 100 kept (in sorted order) -> outputs, zero-pad the rest.
__global__ __launch_bounds__(256) void k_output(
    const float* __restrict__ topk_score, const float* __restrict__ det_box,
    const int* __restrict__ det_label, const int* __restrict__ keep,
    float* __restrict__ out) {
  int b = blockIdx.x, tid = threadIdx.x;
  __shared__ int pf[1024];
  for (int i = tid; i < 1024; i += 256) pf[i] = (i < KTOP) ? keep[b * KTOP + i] : 0;
  __syncthreads();
  for (int d = 1; d < 1024; d <<= 1) {
    int v[4];
#pragma unroll
    for (int k = 0; k < 4; ++k) {
      int i = tid + k * 256;
      v[k] = pf[i] + ((i >= d) ? pf[i - d] : 0);
    }
    __syncthreads();
#pragma unroll
    for (int k = 0; k < 4; ++k) pf[tid + k * 256] = v[k];
    __syncthreads();
  }
  int total = min(pf[KTOP - 1], NDET);
  float* ob = out;
  float* os = out + (size_t)NB * NDET * 4;
  float* ol = os + (size_t)NB * NDET;
  for (int i = tid; i < KTOP; i += 256) {
    if (keep[b * KTOP + i]) {
      int r = pf[i] - 1;
      if (r < NDET) {
        ob[((size_t)b * NDET + r) * 4 + 0] = det_box[((size_t)b * KTOP + i) * 4 + 0];
        ob[((size_t)b * NDET + r) * 4 + 1] = det_box[((size_t)b * KTOP + i) * 4 + 1];
        ob[((size_t)b * NDET + r) * 4 + 2] = det_box[((size_t)b * KTOP + i) * 4 + 2];
        ob[((size_t)b * NDET + r) * 4 + 3] = det_box[((size_t)b * KTOP + i) * 4 + 3];
        os[b * NDET + r] = topk_score[b * KTOP + i];
        ol[b * NDET + r] = (float)det_label[b * KTOP + i];
      }
    }
  }
  for (int r = total + tid; r < NDET; r += 256) {
    ob[((size_t)b * NDET + r) * 4 + 0] = 0.0f;
    ob[((size_t)b * NDET + r) * 4 + 1] = 0.0f;
    ob[((size_t)b * NDET + r) * 4 + 2] = 0.0f;
    ob[((size_t)b * NDET + r) * 4 + 3] = 0.0f;
    os[b * NDET + r] = 0.0f;
    ol[b * NDET + r] = 0.0f;
  }
}

}  // namespace

extern "C" void kernel_launch(void* const* d_in, const int* in_sizes, int n_in,
                              void* d_out, int out_size, void* d_ws, size_t ws_size,
                              hipStream_t stream) {
  const float* logits = (const float*)d_in[0];
  const float* boxreg = (const float*)d_in[1];
  const float* props = (const float*)d_in[2];
  const int* hw = (const int*)d_in[3];

  char* ws = (char*)d_ws;
  size_t off = 0;
  auto alloc = [&](size_t bytes) -> void* {
    void* p = ws + off;
    off += (bytes + 255) & ~(size_t)255;
    return p;
  };
  float* cand_score = (float*)alloc((size_t)NB * CAP * 4);
  int* cand_idx = (int*)alloc((size_t)NB * CAP * 4);
  int* cand_cnt = (int*)alloc(NB * 4);
  float* topk_score = (float*)alloc((size_t)NB * KTOP * 4);
  int* topk_idx = (int*)alloc((size_t)NB * KTOP * 4);
  float* det_box = (float*)alloc((size_t)NB * KTOP * 16);
  int* det_label = (int*)alloc((size_t)NB * KTOP * 4);
  int* det_valid = (int*)alloc((size_t)NB * KTOP * 4);
  unsigned long long* maskmat = (unsigned long long*)alloc((size_t)NB * KTOP * 16 * 8);
  int* keep = (int*)alloc((size_t)NB * KTOP * 4);

  k_zero<<<1, 64, 0, stream>>>(cand_cnt);
  k_candidates<<<(NB * NP) / 4, 256, 0, stream>>>(logits, boxreg, props, hw,
                                                  cand_score, cand_idx, cand_cnt);
  k_select<<<NB, 1024, 0, stream>>>(cand_score, cand_idx, cand_cnt, topk_score, topk_idx);
  k_decode<<<(NB * KTOP + 255) / 256, 256, 0, stream>>>(boxreg, props, hw, topk_idx,
                                                        det_box, det_label, det_valid);
  k_mask<<<(NB * KTOP * 16 + 255) / 256, 256, 0, stream>>>(det_box, det_label, maskmat);
  k_greedy<<<NB, 64, 0, stream>>>(maskmat, det_valid, keep);
  k_output<<<NB, 256, 0, stream>>>(topk_score, det_box, det_label, keep, (float*)d_out);
}

// Round 2
// 315.645 us; speedup vs baseline: 3.6529x; 3.6529x over previous
//
#include <hip/hip_runtime.h>

namespace {

constexpr int NB = 8, NP = 8192, NC = 91;
constexpr int KTOP = 1000, NDET = 100;
constexpr int CAP = 65536;           // per-image candidate capacity (~4x expected 16k)
constexpr int NBUCK = 4096, SORTN = 4096;
constexpr int CNT_STRIDE = 64;       // ints between per-image counters (256B padding)
constexpr float SCORE_T = 0.05f;
constexpr float MIN_SZ = 0.01f;
constexpr float NMS_T = 0.5f;
constexpr float CLIPV = 4.135166556742356f;  // log(1000/16)
constexpr float NEGV = -1e9f;

__device__ __forceinline__ void decode_box(const float4& pr, const float4& rel,
                                           float Wf, float Hf,
                                           float& x1, float& y1, float& x2, float& y2) {
  float w = pr.z - pr.x, h = pr.w - pr.y;
  float cx = pr.x + 0.5f * w, cy = pr.y + 0.5f * h;
  float dx = rel.x / 10.0f, dy = rel.y / 10.0f;
  float dw = fminf(rel.z / 5.0f, CLIPV), dh = fminf(rel.w / 5.0f, CLIPV);
  float pcx = dx * w + cx, pcy = dy * h + cy;
  float pw = expf(dw) * w, ph = expf(dh) * h;
  x1 = fminf(fmaxf(pcx - 0.5f * pw, 0.0f), Wf);
  y1 = fminf(fmaxf(pcy - 0.5f * ph, 0.0f), Hf);
  x2 = fminf(fmaxf(pcx + 0.5f * pw, 0.0f), Wf);
  y2 = fminf(fmaxf(pcy + 0.5f * ph, 0.0f), Hf);
}

__global__ __launch_bounds__(512) void k_zero(int* cand_cnt) {
  if (threadIdx.x < NB * CNT_STRIDE) cand_cnt[threadIdx.x] = 0;
}

// One wave (64 lanes) per proposal, 4 proposals (same image) per block.
// Wave-wide softmax, decode score-passing candidates, block-aggregated append
// (ONE returning atomic per block, to a 256B-padded per-image counter).
__global__ __launch_bounds__(256) void k_candidates(
    const float* __restrict__ logits, const float* __restrict__ boxreg,
    const float* __restrict__ props, const int* __restrict__ hw,
    float* __restrict__ cand_score, int* __restrict__ cand_idx,
    int* __restrict__ cand_cnt) {
  int wid = threadIdx.x >> 6;
  int lane = threadIdx.x & 63;
  int gw = blockIdx.x * 4 + wid;          // proposal index; grid is exact
  int b = gw / NP, p = gw % NP;           // all 4 waves in a block share b
  float Hf = (float)hw[0], Wf = (float)hw[1];
  const float* lrow = logits + (size_t)gw * NC;
  float z0 = (lane < NC) ? lrow[lane] : -3.0e38f;
  float z1 = (lane + 64 < NC) ? lrow[lane + 64] : -3.0e38f;
  float mx = fmaxf(z0, z1);
#pragma unroll
  for (int o = 32; o > 0; o >>= 1) mx = fmaxf(mx, __shfl_xor(mx, o, 64));
  float e0 = (lane < NC) ? expf(z0 - mx) : 0.0f;
  float e1 = (lane + 64 < NC) ? expf(z1 - mx) : 0.0f;
  float sm = e0 + e1;
#pragma unroll
  for (int o = 32; o > 0; o >>= 1) sm += __shfl_xor(sm, o, 64);
  float4 pr = reinterpret_cast<const float4*>(props)[gw];
  const float4* relrow = reinterpret_cast<const float4*>(boxreg + (size_t)gw * 4 * NC);

  float inv_sm = 1.0f / sm;
  // pass 0: classes lane (1..63);  pass 1: classes lane+64 (64..90)
  float sc0 = e0 * inv_sm, sc1 = e1 * inv_sm;
  bool ok0 = (lane >= 1) && (sc0 > SCORE_T);
  bool ok1 = (lane + 64 < NC) && (sc1 > SCORE_T);
  if (ok0) {
    float4 rel = relrow[lane];
    float x1, y1, x2, y2;
    decode_box(pr, rel, Wf, Hf, x1, y1, x2, y2);
    ok0 = ((x2 - x1) >= MIN_SZ) && ((y2 - y1) >= MIN_SZ);
  }
  if (ok1) {
    float4 rel = relrow[lane + 64];
    float x1, y1, x2, y2;
    decode_box(pr, rel, Wf, Hf, x1, y1, x2, y2);
    ok1 = ((x2 - x1) >= MIN_SZ) && ((y2 - y1) >= MIN_SZ);
  }
  unsigned long long mk0 = __ballot(ok0);
  unsigned long long mk1 = __ballot(ok1);
  int n0 = __popcll(mk0);
  int nw = n0 + __popcll(mk1);

  __shared__ int wcnt[4];
  __shared__ int wbase[4];
  if (lane == 0) wcnt[wid] = nw;
  __syncthreads();
  if (threadIdx.x == 0) {
    int t0 = wcnt[0], t1 = wcnt[1], t2 = wcnt[2], t3 = wcnt[3];
    int total = t0 + t1 + t2 + t3;
    int base = total ? atomicAdd(&cand_cnt[b * CNT_STRIDE], total) : 0;
    wbase[0] = base;
    wbase[1] = base + t0;
    wbase[2] = base + t0 + t1;
    wbase[3] = base + t0 + t1 + t2;
  }
  __syncthreads();
  if (!nw) return;
  int base = wbase[wid];
  unsigned long long lmask = (1ull << lane) - 1ull;
  if (ok0) {
    int pos = base + __popcll(mk0 & lmask);
    if (pos < CAP) {
      cand_score[(size_t)b * CAP + pos] = sc0;
      cand_idx[(size_t)b * CAP + pos] = p * (NC - 1) + (lane - 1);
    }
  }
  if (ok1) {
    int pos = base + n0 + __popcll(mk1 & lmask);
    if (pos < CAP) {
      cand_score[(size_t)b * CAP + pos] = sc1;
      cand_idx[(size_t)b * CAP + pos] = p * (NC - 1) + (lane + 63);
    }
  }
}

// Per-image exact top-1000: histogram radix-select on float bits, compact,
// bitonic sort by (score desc, idx asc).
__global__ __launch_bounds__(1024) void k_select(
    const float* __restrict__ cand_score, const int* __restrict__ cand_idx,
    const int* __restrict__ cand_cnt,
    float* __restrict__ topk_score, int* __restrict__ topk_idx) {
  __shared__ int hist[NBUCK];
  __shared__ unsigned long long keys[SORTN];
  __shared__ int ncomp;
  __shared__ int sbound;
  int b = blockIdx.x, tid = threadIdx.x;
  int cnt = min(cand_cnt[b * CNT_STRIDE], CAP);
  for (int i = tid; i < NBUCK; i += 1024) hist[i] = 0;
  if (tid == 0) { ncomp = 0; sbound = 0; }
  __syncthreads();
  const float* cs = cand_score + (size_t)b * CAP;
  const int* ci = cand_idx + (size_t)b * CAP;
  for (int i = tid; i < cnt; i += 1024) {
    unsigned bits = __float_as_uint(cs[i]);
    int bk = min((int)((bits - 0x3D000000u) >> 14), NBUCK - 1);
    atomicAdd(&hist[bk], 1);
  }
  __syncthreads();
  // inclusive suffix scan of hist (count of candidates in buckets >= i)
  for (int d = 1; d < NBUCK; d <<= 1) {
    int v[NBUCK / 1024];
#pragma unroll
    for (int k = 0; k < NBUCK / 1024; ++k) {
      int i = tid + k * 1024;
      v[k] = hist[i] + ((i + d < NBUCK) ? hist[i + d] : 0);
    }
    __syncthreads();
#pragma unroll
    for (int k = 0; k < NBUCK / 1024; ++k) hist[tid + k * 1024] = v[k];
    __syncthreads();
  }
#pragma unroll
  for (int k = 0; k < NBUCK / 1024; ++k) {
    int i = tid + k * 1024;
    if (hist[i] >= KTOP && (i == NBUCK - 1 || hist[i + 1] < KTOP)) sbound = i;
  }
  __syncthreads();
  int bd = sbound;
  for (int i = tid; i < cnt; i += 1024) {
    unsigned bits = __float_as_uint(cs[i]);
    int bk = min((int)((bits - 0x3D000000u) >> 14), NBUCK - 1);
    if (bk >= bd) {
      int pos = atomicAdd(&ncomp, 1);
      if (pos < SORTN)
        keys[pos] = ((unsigned long long)bits << 32) | (unsigned)(~(unsigned)ci[i]);
    }
  }
  __syncthreads();
  int total = min(ncomp, SORTN);
  for (int i = tid; i < SORTN; i += 1024)
    if (i >= total) keys[i] = 0ull;
  __syncthreads();
  // bitonic sort, descending by 64-bit key
  for (int k = 2; k <= SORTN; k <<= 1) {
    for (int j = k >> 1; j > 0; j >>= 1) {
      for (int t = tid; t < SORTN; t += 1024) {
        int ixj = t ^ j;
        if (ixj > t) {
          unsigned long long a = keys[t], c2 = keys[ixj];
          bool up = ((t & k) == 0);
          bool sw = up ? (a < c2) : (a > c2);
          if (sw) { keys[t] = c2; keys[ixj] = a; }
        }
      }
      __syncthreads();
    }
  }
  int valid_n = min(total, KTOP);
  if (tid < KTOP) {
    if (tid < valid_n) {
      unsigned long long key = keys[tid];
      topk_score[b * KTOP + tid] = __uint_as_float((unsigned)(key >> 32));
      topk_idx[b * KTOP + tid] = (int)(~(unsigned)key);
    } else {
      topk_score[b * KTOP + tid] = NEGV;
      topk_idx[b * KTOP + tid] = -1;
    }
  }
}

__global__ __launch_bounds__(256) void k_decode(
    const float* __restrict__ boxreg, const float* __restrict__ props,
    const int* __restrict__ hw, const int* __restrict__ topk_idx,
    float* __restrict__ det_box, int* __restrict__ det_label,
    int* __restrict__ det_valid) {
  int g = blockIdx.x * 256 + threadIdx.x;
  if (g >= NB * KTOP) return;
  int b = g / KTOP;
  int fidx = topk_idx[g];
  if (fidx < 0) {
    det_box[(size_t)g * 4 + 0] = 0.0f;
    det_box[(size_t)g * 4 + 1] = 0.0f;
    det_box[(size_t)g * 4 + 2] = 0.0f;
    det_box[(size_t)g * 4 + 3] = 0.0f;
    det_label[g] = 0;
    det_valid[g] = 0;
    return;
  }
  int p = fidx / (NC - 1), c = fidx % (NC - 1) + 1;
  float Hf = (float)hw[0], Wf = (float)hw[1];
  float4 pr = reinterpret_cast<const float4*>(props)[b * NP + p];
  float4 rel =
      reinterpret_cast<const float4*>(boxreg + (size_t)(b * NP + p) * 4 * NC)[c];
  float x1, y1, x2, y2;
  decode_box(pr, rel, Wf, Hf, x1, y1, x2, y2);
  det_box[(size_t)g * 4 + 0] = x1;
  det_box[(size_t)g * 4 + 1] = y1;
  det_box[(size_t)g * 4 + 2] = x2;
  det_box[(size_t)g * 4 + 3] = y2;
  det_label[g] = c;
  det_valid[g] = 1;
}

// Suppression bit-matrix: bit t of word w of row (b,i) = [j=w*64+t > i, same
// label, IoU > 0.5].  (Class offsets in the reference make cross-class IoU
// exactly 0 since offset_scale=1334 > max coord 1333, so label equality is an
// exact replacement.)
__global__ __launch_bounds__(256) void k_mask(
    const float* __restrict__ det_box, const int* __restrict__ det_label,
    unsigned long long* __restrict__ maskmat) {
  int g = blockIdx.x * 256 + threadIdx.x;
  if (g >= NB * KTOP * 16) return;
  int w = g & 15;
  int i = (g >> 4) % KTOP;
  int b = (g >> 4) / KTOP;
  const float4* bb = reinterpret_cast<const float4*>(det_box) + (size_t)b * KTOP;
  const int* ll = det_label + b * KTOP;
  float4 bi = bb[i];
  int li = ll[i];
  float areai = (bi.z - bi.x) * (bi.w - bi.y);
  unsigned long long bits = 0;
  int j0 = w * 64;
  for (int t = 0; t < 64; ++t) {
    int j = j0 + t;
    if (j > i && j < KTOP && ll[j] == li) {
      float4 bj = bb[j];
      float areaj = (bj.z - bj.x) * (bj.w - bj.y);
      float ltx = fmaxf(bi.x, bj.x), lty = fmaxf(bi.y, bj.y);
      float rbx = fminf(bi.z, bj.z), rby = fminf(bi.w, bj.w);
      float iw = fmaxf(rbx - ltx, 0.0f), ih = fmaxf(rby - lty, 0.0f);
      float inter = iw * ih;
      float iou = inter / (areai + areaj - inter + 1e-9f);
      if (iou > NMS_T) bits |= (1ull << t);
    }
  }
  maskmat[(size_t)(b * KTOP + i) * 16 + w] = bits;
}

// Serial greedy NMS scan: 1 wave per image; lanes 0..15 hold the 1000-bit
// suppression state as uint64 words; 8-row double-buffered register prefetch.
__global__ __launch_bounds__(64) void k_greedy(
    const unsigned long long* __restrict__ maskmat,
    const int* __restrict__ det_valid, int* __restrict__ keep) {
  int b = blockIdx.x;
  int lane = threadIdx.x;
  unsigned long long validw = 0;
#pragma unroll
  for (int w = 0; w < 16; ++w) {
    int j = w * 64 + lane;
    int f = (j < KTOP) ? det_valid[b * KTOP + j] : 0;
    unsigned long long m = __ballot(f != 0);
    if (lane == w) validw = m;
  }
  unsigned long long supp = 0;
  const unsigned long long* mrow = maskmat + (size_t)b * KTOP * 16;
  int wl = (lane < 16) ? lane : 0;
  unsigned long long cur[8], nxt[8];
#pragma unroll
  for (int r = 0; r < 8; ++r) cur[r] = mrow[(size_t)r * 16 + wl];
  for (int t0 = 0; t0 < KTOP; t0 += 8) {
    int nt0 = t0 + 8;
#pragma unroll
    for (int r = 0; r < 8; ++r) {
      int row = nt0 + r;
      nxt[r] = (row < KTOP) ? mrow[(size_t)row * 16 + wl] : 0ull;
    }
#pragma unroll
    for (int r = 0; r < 8; ++r) {
      int i = t0 + r;
      if (i < KTOP) {
        int w = i >> 6, bit = i & 63;
        unsigned long long sw = ((unsigned long long)(unsigned)__shfl((int)(supp >> 32), w, 64) << 32) |
                                (unsigned)__shfl((int)(supp & 0xffffffffull), w, 64);
        unsigned long long vw = ((unsigned long long)(unsigned)__shfl((int)(validw >> 32), w, 64) << 32) |
                                (unsigned)__shfl((int)(validw & 0xffffffffull), w, 64);
        bool active = (((sw >> bit) & 1ull) == 0ull) && (((vw >> bit) & 1ull) != 0ull);
        if (active) supp |= cur[r];
      }
    }
#pragma unroll
    for (int r = 0; r < 8; ++r) cur[r] = nxt[r];
  }
  if (lane < 16) {
    for (int bit = 0; bit < 64; ++bit) {
      int i = lane * 64 + bit;
      if (i < KTOP)
        keep[b * KTOP + i] =
            ((((supp >> bit) & 1ull) == 0ull) && (((validw >> bit) & 1ull) != 0ull)) ? 1 : 0;
    }
  }
}

// First 100 kept (in sorted order) -> outputs, zero-pad the rest.
__global__ __launch_bounds__(256) void k_output(
    const float* __restrict__ topk_score, const float* __restrict__ det_box,
    const int* __restrict__ det_label, const int* __restrict__ keep,
    float* __restrict__ out) {
  int b = blockIdx.x, tid = threadIdx.x;
  __shared__ int pf[1024];
  for (int i = tid; i < 1024; i += 256) pf[i] = (i < KTOP) ? keep[b * KTOP + i] : 0;
  __syncthreads();
  for (int d = 1; d < 1024; d <<= 1) {
    int v[4];
#pragma unroll
    for (int k = 0; k < 4; ++k) {
      int i = tid + k * 256;
      v[k] = pf[i] + ((i >= d) ? pf[i - d] : 0);
    }
    __syncthreads();
#pragma unroll
    for (int k = 0; k < 4; ++k) pf[tid + k * 256] = v[k];
    __syncthreads();
  }
  int total = min(pf[KTOP - 1], NDET);
  float* ob = out;
  float* os = out + (size_t)NB * NDET * 4;
  float* ol = os + (size_t)NB * NDET;
  for (int i = tid; i < KTOP; i += 256) {
    if (keep[b * KTOP + i]) {
      int r = pf[i] - 1;
      if (r < NDET) {
        ob[((size_t)b * NDET + r) * 4 + 0] = det_box[((size_t)b * KTOP + i) * 4 + 0];
        ob[((size_t)b * NDET + r) * 4 + 1] = det_box[((size_t)b * KTOP + i) * 4 + 1];
        ob[((size_t)b * NDET + r) * 4 + 2] = det_box[((size_t)b * KTOP + i) * 4 + 2];
        ob[((size_t)b * NDET + r) * 4 + 3] = det_box[((size_t)b * KTOP + i) * 4 + 3];
        os[b * NDET + r] = topk_score[b * KTOP + i];
        ol[b * NDET + r] = (float)det_label[b * KTOP + i];
      }
    }
  }
  for (int r = total + tid; r < NDET; r += 256) {
    ob[((size_t)b * NDET + r) * 4 + 0] = 0.0f;
    ob[((size_t)b * NDET + r) * 4 + 1] = 0.0f;
    ob[((size_t)b * NDET + r) * 4 + 2] = 0.0f;
    ob[((size_t)b * NDET + r) * 4 + 3] = 0.0f;
    os[b * NDET + r] = 0.0f;
    ol[b * NDET + r] = 0.0f;
  }
}

}  // namespace

extern "C" void kernel_launch(void* const* d_in, const int* in_sizes, int n_in,
                              void* d_out, int out_size, void* d_ws, size_t ws_size,
                              hipStream_t stream) {
  const float* logits = (const float*)d_in[0];
  const float* boxreg = (const float*)d_in[1];
  const float* props = (const float*)d_in[2];
  const int* hw = (const int*)d_in[3];

  char* ws = (char*)d_ws;
  size_t off = 0;
  auto alloc = [&](size_t bytes) -> void* {
    void* p = ws + off;
    off += (bytes + 255) & ~(size_t)255;
    return p;
  };
  float* cand_score = (float*)alloc((size_t)NB * CAP * 4);
  int* cand_idx = (int*)alloc((size_t)NB * CAP * 4);
  int* cand_cnt = (int*)alloc((size_t)NB * CNT_STRIDE * 4);
  float* topk_score = (float*)alloc((size_t)NB * KTOP * 4);
  int* topk_idx = (int*)alloc((size_t)NB * KTOP * 4);
  float* det_box = (float*)alloc((size_t)NB * KTOP * 16);
  int* det_label = (int*)alloc((size_t)NB * KTOP * 4);
  int* det_valid = (int*)alloc((size_t)NB * KTOP * 4);
  unsigned long long* maskmat = (unsigned long long*)alloc((size_t)NB * KTOP * 16 * 8);
  int* keep = (int*)alloc((size_t)NB * KTOP * 4);

  k_zero<<<1, 512, 0, stream>>>(cand_cnt);
  k_candidates<<<(NB * NP) / 4, 256, 0, stream>>>(logits, boxreg, props, hw,
                                                  cand_score, cand_idx, cand_cnt);
  k_select<<<NB, 1024, 0, stream>>>(cand_score, cand_idx, cand_cnt, topk_score, topk_idx);
  k_decode<<<(NB * KTOP + 255) / 256, 256, 0, stream>>>(boxreg, props, hw, topk_idx,
                                                        det_box, det_label, det_valid);
  k_mask<<<(NB * KTOP * 16 + 255) / 256, 256, 0, stream>>>(det_box, det_label, maskmat);
  k_greedy<<<NB, 64, 0, stream>>>(maskmat, det_valid, keep);
  k_output<<<NB, 256, 0, stream>>>(topk_score, det_box, det_label, keep, (float*)d_out);
}

// Round 3
// 248.641 us; speedup vs baseline: 4.6373x; 1.2695x over previous
//
#include <hip/hip_runtime.h>

namespace {

constexpr int NB = 8, NP = 8192, NC = 91;
constexpr int KTOP = 1000, NDET = 100;
constexpr int SLOTS = 24;            // max candidates/proposal: scores sum<=1 => <=19 can be >0.05
constexpr int NBUCK = 4096, SORTN = 4096;
constexpr float SCORE_T = 0.05f;
constexpr float MIN_SZ = 0.01f;
constexpr float NMS_T = 0.5f;
constexpr float CLIPV = 4.135166556742356f;  // log(1000/16)
constexpr float NEGV = -1e9f;

typedef unsigned long long ull;

__device__ __forceinline__ void decode_box(const float4& pr, const float4& rel,
                                           float Wf, float Hf,
                                           float& x1, float& y1, float& x2, float& y2) {
  float w = pr.z - pr.x, h = pr.w - pr.y;
  float cx = pr.x + 0.5f * w, cy = pr.y + 0.5f * h;
  float dx = rel.x / 10.0f, dy = rel.y / 10.0f;
  float dw = fminf(rel.z / 5.0f, CLIPV), dh = fminf(rel.w / 5.0f, CLIPV);
  float pcx = dx * w + cx, pcy = dy * h + cy;
  float pw = expf(dw) * w, ph = expf(dh) * h;
  x1 = fminf(fmaxf(pcx - 0.5f * pw, 0.0f), Wf);
  y1 = fminf(fmaxf(pcy - 0.5f * ph, 0.0f), Hf);
  x2 = fminf(fmaxf(pcx + 0.5f * pw, 0.0f), Wf);
  y2 = fminf(fmaxf(pcy + 0.5f * ph, 0.0f), Hf);
}

__device__ __forceinline__ int score_bucket(unsigned bits) {
  return min((int)((bits - 0x3D000000u) >> 14), NBUCK - 1);
}

__global__ __launch_bounds__(256) void k_zero(int* ghist) {
  int g = blockIdx.x * 256 + threadIdx.x;
  if (g < NB * NBUCK) ghist[g] = 0;
}

// One wave per proposal, deterministic 24-slot output region per proposal:
// NO contended atomics. Histogram updates are fire-and-forget atomics spread
// over NB*4096 addresses.
__global__ __launch_bounds__(256) void k_candidates(
    const float* __restrict__ logits, const float* __restrict__ boxreg,
    const float* __restrict__ props, const int* __restrict__ hw,
    ull* __restrict__ keys, int* __restrict__ pcount, int* __restrict__ ghist) {
  int wid = threadIdx.x >> 6;
  int lane = threadIdx.x & 63;
  int gw = blockIdx.x * 4 + wid;          // proposal index; grid exact
  int b = gw / NP, p = gw % NP;
  float Hf = (float)hw[0], Wf = (float)hw[1];
  const float* lrow = logits + (size_t)gw * NC;
  float z0 = (lane < NC) ? lrow[lane] : -3.0e38f;
  float z1 = (lane + 64 < NC) ? lrow[lane + 64] : -3.0e38f;
  float mx = fmaxf(z0, z1);
#pragma unroll
  for (int o = 32; o > 0; o >>= 1) mx = fmaxf(mx, __shfl_xor(mx, o, 64));
  float e0 = (lane < NC) ? expf(z0 - mx) : 0.0f;
  float e1 = (lane + 64 < NC) ? expf(z1 - mx) : 0.0f;
  float sm = e0 + e1;
#pragma unroll
  for (int o = 32; o > 0; o >>= 1) sm += __shfl_xor(sm, o, 64);
  float4 pr = reinterpret_cast<const float4*>(props)[gw];
  const float4* relrow = reinterpret_cast<const float4*>(boxreg + (size_t)gw * 4 * NC);

  float inv_sm = 1.0f / sm;
  float sc0 = e0 * inv_sm, sc1 = e1 * inv_sm;
  bool ok0 = (lane >= 1) && (sc0 > SCORE_T);
  bool ok1 = (lane + 64 < NC) && (sc1 > SCORE_T);
  if (ok0) {
    float4 rel = relrow[lane];
    float x1, y1, x2, y2;
    decode_box(pr, rel, Wf, Hf, x1, y1, x2, y2);
    ok0 = ((x2 - x1) >= MIN_SZ) && ((y2 - y1) >= MIN_SZ);
  }
  if (ok1) {
    float4 rel = relrow[lane + 64];
    float x1, y1, x2, y2;
    decode_box(pr, rel, Wf, Hf, x1, y1, x2, y2);
    ok1 = ((x2 - x1) >= MIN_SZ) && ((y2 - y1) >= MIN_SZ);
  }
  unsigned long long mk0 = __ballot(ok0);
  unsigned long long mk1 = __ballot(ok1);
  int n0 = __popcll(mk0);
  int nw = n0 + __popcll(mk1);
  unsigned long long lmask = (1ull << lane) - 1ull;
  ull* krow = keys + (size_t)gw * SLOTS;
  if (ok0) {
    int pos = __popcll(mk0 & lmask);
    unsigned bits = __float_as_uint(sc0);
    int idx = p * (NC - 1) + (lane - 1);
    if (pos < SLOTS) krow[pos] = ((ull)bits << 32) | (unsigned)(~(unsigned)idx);
    atomicAdd(&ghist[b * NBUCK + score_bucket(bits)], 1);
  }
  if (ok1) {
    int pos = n0 + __popcll(mk1 & lmask);
    unsigned bits = __float_as_uint(sc1);
    int idx = p * (NC - 1) + (lane + 63);
    if (pos < SLOTS) krow[pos] = ((ull)bits << 32) | (unsigned)(~(unsigned)idx);
    atomicAdd(&ghist[b * NBUCK + score_bucket(bits)], 1);
  }
  if (lane == 0) pcount[gw] = min(nw, SLOTS);
}

// Per image: inclusive suffix scan of histogram -> threshold bucket, per-bucket
// output cursors (exclusive suffix offsets), and compact total.
__global__ __launch_bounds__(1024) void k_bound(
    const int* __restrict__ ghist, int* __restrict__ ccur,
    int* __restrict__ sboundA, int* __restrict__ ctotal) {
  __shared__ int h[NBUCK];
  __shared__ int sb;
  int b = blockIdx.x, tid = threadIdx.x;
#pragma unroll
  for (int k = 0; k < NBUCK / 1024; ++k) h[tid + k * 1024] = ghist[b * NBUCK + tid + k * 1024];
  if (tid == 0) sb = 0;
  __syncthreads();
  for (int d = 1; d < NBUCK; d <<= 1) {
    int v[NBUCK / 1024];
#pragma unroll
    for (int k = 0; k < NBUCK / 1024; ++k) {
      int i = tid + k * 1024;
      v[k] = h[i] + ((i + d < NBUCK) ? h[i + d] : 0);
    }
    __syncthreads();
#pragma unroll
    for (int k = 0; k < NBUCK / 1024; ++k) h[tid + k * 1024] = v[k];
    __syncthreads();
  }
#pragma unroll
  for (int k = 0; k < NBUCK / 1024; ++k) {
    int i = tid + k * 1024;
    if (h[i] >= KTOP && (i == NBUCK - 1 || h[i + 1] < KTOP)) sb = i;
  }
  __syncthreads();
#pragma unroll
  for (int k = 0; k < NBUCK / 1024; ++k) {
    int i = tid + k * 1024;
    ccur[b * NBUCK + i] = (i + 1 < NBUCK) ? h[i + 1] : 0;
  }
  if (tid == 0) {
    sboundA[b] = sb;
    ctotal[b] = h[sb];
  }
}

// Scatter passing candidates to per-bucket cursor positions (atomics spread
// over ~hundreds of bucket cursors; positions are globally unique in [0,total)).
__global__ __launch_bounds__(256) void k_compact(
    const ull* __restrict__ keys, const int* __restrict__ pcount,
    const int* __restrict__ sboundA, int* __restrict__ ccur,
    ull* __restrict__ ckeys) {
  int g = blockIdx.x * 256 + threadIdx.x;   // < NB*NP*SLOTS, grid exact
  int slot = g % SLOTS;
  int pp = g / SLOTS;
  int b = pp >> 13;                          // NP = 8192
  if (slot >= pcount[pp]) return;
  ull key = keys[g];
  int bk = score_bucket((unsigned)(key >> 32));
  if (bk < sboundA[b]) return;
  int pos = atomicAdd(&ccur[b * NBUCK + bk], 1);
  if (pos < SORTN) ckeys[(size_t)b * SORTN + pos] = key;
}

// Per-image bitonic sort of compacted keys (score desc, idx asc) -> top-1000.
__global__ __launch_bounds__(1024) void k_sort(
    const ull* __restrict__ ckeys, const int* __restrict__ ctotal,
    float* __restrict__ topk_score, int* __restrict__ topk_idx) {
  __shared__ ull skeys[SORTN];
  int b = blockIdx.x, tid = threadIdx.x;
  int total = min(ctotal[b], SORTN);
  for (int i = tid; i < SORTN; i += 1024)
    skeys[i] = (i < total) ? ckeys[(size_t)b * SORTN + i] : 0ull;
  __syncthreads();
  for (int k = 2; k <= SORTN; k <<= 1) {
    for (int j = k >> 1; j > 0; j >>= 1) {
      for (int t = tid; t < SORTN; t += 1024) {
        int ixj = t ^ j;
        if (ixj > t) {
          ull a = skeys[t], c2 = skeys[ixj];
          bool up = ((t & k) == 0);
          bool sw = up ? (a < c2) : (a > c2);
          if (sw) { skeys[t] = c2; skeys[ixj] = a; }
        }
      }
      __syncthreads();
    }
  }
  int valid_n = min(total, KTOP);
  if (tid < KTOP) {
    if (tid < valid_n) {
      ull key = skeys[tid];
      topk_score[b * KTOP + tid] = __uint_as_float((unsigned)(key >> 32));
      topk_idx[b * KTOP + tid] = (int)(~(unsigned)key);
    } else {
      topk_score[b * KTOP + tid] = NEGV;
      topk_idx[b * KTOP + tid] = -1;
    }
  }
}

__global__ __launch_bounds__(256) void k_decode(
    const float* __restrict__ boxreg, const float* __restrict__ props,
    const int* __restrict__ hw, const int* __restrict__ topk_idx,
    float* __restrict__ det_box, int* __restrict__ det_label,
    int* __restrict__ det_valid) {
  int g = blockIdx.x * 256 + threadIdx.x;
  if (g >= NB * KTOP) return;
  int b = g / KTOP;
  int fidx = topk_idx[g];
  if (fidx < 0) {
    det_box[(size_t)g * 4 + 0] = 0.0f;
    det_box[(size_t)g * 4 + 1] = 0.0f;
    det_box[(size_t)g * 4 + 2] = 0.0f;
    det_box[(size_t)g * 4 + 3] = 0.0f;
    det_label[g] = 0;
    det_valid[g] = 0;
    return;
  }
  int p = fidx / (NC - 1), c = fidx % (NC - 1) + 1;
  float Hf = (float)hw[0], Wf = (float)hw[1];
  float4 pr = reinterpret_cast<const float4*>(props)[b * NP + p];
  float4 rel =
      reinterpret_cast<const float4*>(boxreg + (size_t)(b * NP + p) * 4 * NC)[c];
  float x1, y1, x2, y2;
  decode_box(pr, rel, Wf, Hf, x1, y1, x2, y2);
  det_box[(size_t)g * 4 + 0] = x1;
  det_box[(size_t)g * 4 + 1] = y1;
  det_box[(size_t)g * 4 + 2] = x2;
  det_box[(size_t)g * 4 + 3] = y2;
  det_label[g] = c;
  det_valid[g] = 1;
}

// Suppression bit-matrix (labels-equal == class-offset NMS exactly, since
// offset_scale=1334 > max coord 1333 makes cross-class IoU 0).
__global__ __launch_bounds__(256) void k_mask(
    const float* __restrict__ det_box, const int* __restrict__ det_label,
    ull* __restrict__ maskmat) {
  int g = blockIdx.x * 256 + threadIdx.x;
  if (g >= NB * KTOP * 16) return;
  int w = g & 15;
  int i = (g >> 4) % KTOP;
  int b = (g >> 4) / KTOP;
  const float4* bb = reinterpret_cast<const float4*>(det_box) + (size_t)b * KTOP;
  const int* ll = det_label + b * KTOP;
  float4 bi = bb[i];
  int li = ll[i];
  float areai = (bi.z - bi.x) * (bi.w - bi.y);
  ull bits = 0;
  int j0 = w * 64;
  for (int t = 0; t < 64; ++t) {
    int j = j0 + t;
    if (j > i && j < KTOP && ll[j] == li) {
      float4 bj = bb[j];
      float areaj = (bj.z - bj.x) * (bj.w - bj.y);
      float ltx = fmaxf(bi.x, bj.x), lty = fmaxf(bi.y, bj.y);
      float rbx = fminf(bi.z, bj.z), rby = fminf(bi.w, bj.w);
      float iw = fmaxf(rbx - ltx, 0.0f), ih = fmaxf(rby - lty, 0.0f);
      float inter = iw * ih;
      float iou = inter / (areai + areaj - inter + 1e-9f);
      if (iou > NMS_T) bits |= (1ull << t);
    }
  }
  maskmat[(size_t)(b * KTOP + i) * 16 + w] = bits;
}

// Serial greedy NMS scan: valid folded into initial suppression (halves DS ops).
__global__ __launch_bounds__(64) void k_greedy(
    const ull* __restrict__ maskmat, const int* __restrict__ det_valid,
    int* __restrict__ keep) {
  int b = blockIdx.x;
  int lane = threadIdx.x;
  ull validw = 0;
#pragma unroll
  for (int w = 0; w < 16; ++w) {
    int j = w * 64 + lane;
    int f = (j < KTOP) ? det_valid[b * KTOP + j] : 0;
    ull m = __ballot(f != 0);
    if (lane == w) validw = m;
  }
  ull supp = ~validw;  // invalid == pre-suppressed
  const ull* mrow = maskmat + (size_t)b * KTOP * 16;
  int wl = (lane < 16) ? lane : 0;
  ull cur[8], nxt[8];
#pragma unroll
  for (int r = 0; r < 8; ++r) cur[r] = mrow[(size_t)r * 16 + wl];
  for (int t0 = 0; t0 < KTOP; t0 += 8) {
    int nt0 = t0 + 8;
#pragma unroll
    for (int r = 0; r < 8; ++r) {
      int row = nt0 + r;
      nxt[r] = (row < KTOP) ? mrow[(size_t)row * 16 + wl] : 0ull;
    }
#pragma unroll
    for (int r = 0; r < 8; ++r) {
      int i = t0 + r;
      if (i < KTOP) {
        int w = i >> 6, bit = i & 63;
        ull sw = ((ull)(unsigned)__shfl((int)(supp >> 32), w, 64) << 32) |
                 (unsigned)__shfl((int)(supp & 0xffffffffull), w, 64);
        if (((sw >> bit) & 1ull) == 0ull) supp |= cur[r];
      }
    }
#pragma unroll
    for (int r = 0; r < 8; ++r) cur[r] = nxt[r];
  }
  if (lane < 16) {
    for (int bit = 0; bit < 64; ++bit) {
      int i = lane * 64 + bit;
      if (i < KTOP)
        keep[b * KTOP + i] =
            ((((supp >> bit) & 1ull) == 0ull) && (((validw >> bit) & 1ull) != 0ull)) ? 1 : 0;
    }
  }
}

// First 100 kept (in sorted order) -> outputs, zero-pad the rest.
__global__ __launch_bounds__(256) void k_output(
    const float* __restrict__ topk_score, const float* __restrict__ det_box,
    const int* __restrict__ det_label, const int* __restrict__ keep,
    float* __restrict__ out) {
  int b = blockIdx.x, tid = threadIdx.x;
  __shared__ int pf[1024];
  for (int i = tid; i < 1024; i += 256) pf[i] = (i < KTOP) ? keep[b * KTOP + i] : 0;
  __syncthreads();
  for (int d = 1; d < 1024; d <<= 1) {
    int v[4];
#pragma unroll
    for (int k = 0; k < 4; ++k) {
      int i = tid + k * 256;
      v[k] = pf[i] + ((i >= d) ? pf[i - d] : 0);
    }
    __syncthreads();
#pragma unroll
    for (int k = 0; k < 4; ++k) pf[tid + k * 256] = v[k];
    __syncthreads();
  }
  int total = min(pf[KTOP - 1], NDET);
  float* ob = out;
  float* os = out + (size_t)NB * NDET * 4;
  float* ol = os + (size_t)NB * NDET;
  for (int i = tid; i < KTOP; i += 256) {
    if (keep[b * KTOP + i]) {
      int r = pf[i] - 1;
      if (r < NDET) {
        ob[((size_t)b * NDET + r) * 4 + 0] = det_box[((size_t)b * KTOP + i) * 4 + 0];
        ob[((size_t)b * NDET + r) * 4 + 1] = det_box[((size_t)b * KTOP + i) * 4 + 1];
        ob[((size_t)b * NDET + r) * 4 + 2] = det_box[((size_t)b * KTOP + i) * 4 + 2];
        ob[((size_t)b * NDET + r) * 4 + 3] = det_box[((size_t)b * KTOP + i) * 4 + 3];
        os[b * NDET + r] = topk_score[b * KTOP + i];
        ol[b * NDET + r] = (float)det_label[b * KTOP + i];
      }
    }
  }
  for (int r = total + tid; r < NDET; r += 256) {
    ob[((size_t)b * NDET + r) * 4 + 0] = 0.0f;
    ob[((size_t)b * NDET + r) * 4 + 1] = 0.0f;
    ob[((size_t)b * NDET + r) * 4 + 2] = 0.0f;
    ob[((size_t)b * NDET + r) * 4 + 3] = 0.0f;
    os[b * NDET + r] = 0.0f;
    ol[b * NDET + r] = 0.0f;
  }
}

}  // namespace

extern "C" void kernel_launch(void* const* d_in, const int* in_sizes, int n_in,
                              void* d_out, int out_size, void* d_ws, size_t ws_size,
                              hipStream_t stream) {
  const float* logits = (const float*)d_in[0];
  const float* boxreg = (const float*)d_in[1];
  const float* props = (const float*)d_in[2];
  const int* hw = (const int*)d_in[3];

  char* ws = (char*)d_ws;
  size_t off = 0;
  auto alloc = [&](size_t bytes) -> void* {
    void* p = ws + off;
    off += (bytes + 255) & ~(size_t)255;
    return p;
  };
  ull* keys = (ull*)alloc((size_t)NB * NP * SLOTS * 8);
  int* pcount = (int*)alloc((size_t)NB * NP * 4);
  int* ghist = (int*)alloc((size_t)NB * NBUCK * 4);
  int* ccur = (int*)alloc((size_t)NB * NBUCK * 4);
  int* sboundA = (int*)alloc(NB * 4);
  int* ctotal = (int*)alloc(NB * 4);
  ull* ckeys = (ull*)alloc((size_t)NB * SORTN * 8);
  float* topk_score = (float*)alloc((size_t)NB * KTOP * 4);
  int* topk_idx = (int*)alloc((size_t)NB * KTOP * 4);
  float* det_box = (float*)alloc((size_t)NB * KTOP * 16);
  int* det_label = (int*)alloc((size_t)NB * KTOP * 4);
  int* det_valid = (int*)alloc((size_t)NB * KTOP * 4);
  ull* maskmat = (ull*)alloc((size_t)NB * KTOP * 16 * 8);
  int* keep = (int*)alloc((size_t)NB * KTOP * 4);

  k_zero<<<(NB * NBUCK + 255) / 256, 256, 0, stream>>>(ghist);
  k_candidates<<<(NB * NP) / 4, 256, 0, stream>>>(logits, boxreg, props, hw,
                                                  keys, pcount, ghist);
  k_bound<<<NB, 1024, 0, stream>>>(ghist, ccur, sboundA, ctotal);
  k_compact<<<(NB * NP * SLOTS) / 256, 256, 0, stream>>>(keys, pcount, sboundA, ccur, ckeys);
  k_sort<<<NB, 1024, 0, stream>>>(ckeys, ctotal, topk_score, topk_idx);
  k_decode<<<(NB * KTOP + 255) / 256, 256, 0, stream>>>(boxreg, props, hw, topk_idx,
                                                        det_box, det_label, det_valid);
  k_mask<<<(NB * KTOP * 16 + 255) / 256, 256, 0, stream>>>(det_box, det_label, maskmat);
  k_greedy<<<NB, 64, 0, stream>>>(maskmat, det_valid, keep);
  k_output<<<NB, 256, 0, stream>>>(topk_score, det_box, det_label, keep, (float*)d_out);
}

// Round 4
// 211.817 us; speedup vs baseline: 5.4435x; 1.1738x over previous
//
#include <hip/hip_runtime.h>

namespace {

constexpr int NB = 8, NP = 8192, NC = 91;
constexpr int KTOP = 1000, NDET = 100;
constexpr int MROWS = 1024;          // padded mask rows per image (16 windows of 64)
constexpr int SLOTS = 24;            // max candidates/proposal: scores sum<=1 => <=19 can be >0.05
constexpr int NBUCK = 4096, SORTN = 4096;
constexpr float SCORE_T = 0.05f;
constexpr float MIN_SZ = 0.01f;
constexpr float NMS_T = 0.5f;
constexpr float CLIPV = 4.135166556742356f;  // log(1000/16)
constexpr float NEGV = -1e9f;

typedef unsigned long long ull;

__device__ __forceinline__ void decode_box(const float4& pr, const float4& rel,
                                           float Wf, float Hf,
                                           float& x1, float& y1, float& x2, float& y2) {
  float w = pr.z - pr.x, h = pr.w - pr.y;
  float cx = pr.x + 0.5f * w, cy = pr.y + 0.5f * h;
  float dx = rel.x / 10.0f, dy = rel.y / 10.0f;
  float dw = fminf(rel.z / 5.0f, CLIPV), dh = fminf(rel.w / 5.0f, CLIPV);
  float pcx = dx * w + cx, pcy = dy * h + cy;
  float pw = expf(dw) * w, ph = expf(dh) * h;
  x1 = fminf(fmaxf(pcx - 0.5f * pw, 0.0f), Wf);
  y1 = fminf(fmaxf(pcy - 0.5f * ph, 0.0f), Hf);
  x2 = fminf(fmaxf(pcx + 0.5f * pw, 0.0f), Wf);
  y2 = fminf(fmaxf(pcy + 0.5f * ph, 0.0f), Hf);
}

__device__ __forceinline__ int score_bucket(unsigned bits) {
  return min((int)((bits - 0x3D000000u) >> 14), NBUCK - 1);
}

__device__ __forceinline__ ull shfl64(ull v, int src) {
  int lo = __shfl((int)(unsigned)(v & 0xffffffffull), src, 64);
  int hi = __shfl((int)(unsigned)(v >> 32), src, 64);
  return ((ull)(unsigned)hi << 32) | (unsigned)lo;
}

__device__ __forceinline__ ull shfl_xor64(ull v, int d) {
  int lo = __shfl_xor((int)(unsigned)(v & 0xffffffffull), d, 64);
  int hi = __shfl_xor((int)(unsigned)(v >> 32), d, 64);
  return ((ull)(unsigned)hi << 32) | (unsigned)lo;
}

__global__ __launch_bounds__(256) void k_zero(int* ghist) {
  int g = blockIdx.x * 256 + threadIdx.x;
  if (g < NB * NBUCK) ghist[g] = 0;
}

// One wave per proposal, deterministic 24-slot output region per proposal:
// NO contended atomics. Histogram updates are fire-and-forget atomics spread
// over NB*4096 addresses.
__global__ __launch_bounds__(256) void k_candidates(
    const float* __restrict__ logits, const float* __restrict__ boxreg,
    const float* __restrict__ props, const int* __restrict__ hw,
    ull* __restrict__ keys, int* __restrict__ pcount, int* __restrict__ ghist) {
  int wid = threadIdx.x >> 6;
  int lane = threadIdx.x & 63;
  int gw = blockIdx.x * 4 + wid;          // proposal index; grid exact
  int b = gw / NP, p = gw % NP;
  float Hf = (float)hw[0], Wf = (float)hw[1];
  const float* lrow = logits + (size_t)gw * NC;
  float z0 = (lane < NC) ? lrow[lane] : -3.0e38f;
  float z1 = (lane + 64 < NC) ? lrow[lane + 64] : -3.0e38f;
  float mx = fmaxf(z0, z1);
#pragma unroll
  for (int o = 32; o > 0; o >>= 1) mx = fmaxf(mx, __shfl_xor(mx, o, 64));
  float e0 = (lane < NC) ? expf(z0 - mx) : 0.0f;
  float e1 = (lane + 64 < NC) ? expf(z1 - mx) : 0.0f;
  float sm = e0 + e1;
#pragma unroll
  for (int o = 32; o > 0; o >>= 1) sm += __shfl_xor(sm, o, 64);
  float4 pr = reinterpret_cast<const float4*>(props)[gw];
  const float4* relrow = reinterpret_cast<const float4*>(boxreg + (size_t)gw * 4 * NC);

  float inv_sm = 1.0f / sm;
  float sc0 = e0 * inv_sm, sc1 = e1 * inv_sm;
  bool ok0 = (lane >= 1) && (sc0 > SCORE_T);
  bool ok1 = (lane + 64 < NC) && (sc1 > SCORE_T);
  if (ok0) {
    float4 rel = relrow[lane];
    float x1, y1, x2, y2;
    decode_box(pr, rel, Wf, Hf, x1, y1, x2, y2);
    ok0 = ((x2 - x1) >= MIN_SZ) && ((y2 - y1) >= MIN_SZ);
  }
  if (ok1) {
    float4 rel = relrow[lane + 64];
    float x1, y1, x2, y2;
    decode_box(pr, rel, Wf, Hf, x1, y1, x2, y2);
    ok1 = ((x2 - x1) >= MIN_SZ) && ((y2 - y1) >= MIN_SZ);
  }
  unsigned long long mk0 = __ballot(ok0);
  unsigned long long mk1 = __ballot(ok1);
  int n0 = __popcll(mk0);
  int nw = n0 + __popcll(mk1);
  unsigned long long lmask = (1ull << lane) - 1ull;
  ull* krow = keys + (size_t)gw * SLOTS;
  if (ok0) {
    int pos = __popcll(mk0 & lmask);
    unsigned bits = __float_as_uint(sc0);
    int idx = p * (NC - 1) + (lane - 1);
    if (pos < SLOTS) krow[pos] = ((ull)bits << 32) | (unsigned)(~(unsigned)idx);
    atomicAdd(&ghist[b * NBUCK + score_bucket(bits)], 1);
  }
  if (ok1) {
    int pos = n0 + __popcll(mk1 & lmask);
    unsigned bits = __float_as_uint(sc1);
    int idx = p * (NC - 1) + (lane + 63);
    if (pos < SLOTS) krow[pos] = ((ull)bits << 32) | (unsigned)(~(unsigned)idx);
    atomicAdd(&ghist[b * NBUCK + score_bucket(bits)], 1);
  }
  if (lane == 0) pcount[gw] = min(nw, SLOTS);
}

// Per image: inclusive suffix scan of histogram -> threshold bucket, per-bucket
// output cursors (exclusive suffix offsets), and compact total.
__global__ __launch_bounds__(1024) void k_bound(
    const int* __restrict__ ghist, int* __restrict__ ccur,
    int* __restrict__ sboundA, int* __restrict__ ctotal) {
  __shared__ int h[NBUCK];
  __shared__ int sb;
  int b = blockIdx.x, tid = threadIdx.x;
#pragma unroll
  for (int k = 0; k < NBUCK / 1024; ++k) h[tid + k * 1024] = ghist[b * NBUCK + tid + k * 1024];
  if (tid == 0) sb = 0;
  __syncthreads();
  for (int d = 1; d < NBUCK; d <<= 1) {
    int v[NBUCK / 1024];
#pragma unroll
    for (int k = 0; k < NBUCK / 1024; ++k) {
      int i = tid + k * 1024;
      v[k] = h[i] + ((i + d < NBUCK) ? h[i + d] : 0);
    }
    __syncthreads();
#pragma unroll
    for (int k = 0; k < NBUCK / 1024; ++k) h[tid + k * 1024] = v[k];
    __syncthreads();
  }
#pragma unroll
  for (int k = 0; k < NBUCK / 1024; ++k) {
    int i = tid + k * 1024;
    if (h[i] >= KTOP && (i == NBUCK - 1 || h[i + 1] < KTOP)) sb = i;
  }
  __syncthreads();
#pragma unroll
  for (int k = 0; k < NBUCK / 1024; ++k) {
    int i = tid + k * 1024;
    ccur[b * NBUCK + i] = (i + 1 < NBUCK) ? h[i + 1] : 0;
  }
  if (tid == 0) {
    sboundA[b] = sb;
    ctotal[b] = h[sb];
  }
}

// Scatter passing candidates to per-bucket cursor positions (atomics spread
// over ~hundreds of bucket cursors; positions are globally unique in [0,total)).
__global__ __launch_bounds__(256) void k_compact(
    const ull* __restrict__ keys, const int* __restrict__ pcount,
    const int* __restrict__ sboundA, int* __restrict__ ccur,
    ull* __restrict__ ckeys) {
  int g = blockIdx.x * 256 + threadIdx.x;   // < NB*NP*SLOTS, grid exact
  int slot = g % SLOTS;
  int pp = g / SLOTS;
  int b = pp >> 13;                          // NP = 8192
  if (slot >= pcount[pp]) return;
  ull key = keys[g];
  int bk = score_bucket((unsigned)(key >> 32));
  if (bk < sboundA[b]) return;
  int pos = atomicAdd(&ccur[b * NBUCK + bk], 1);
  if (pos < SORTN) ckeys[(size_t)b * SORTN + pos] = key;
}

// Per-image bitonic sort of compacted keys (score desc, idx asc) -> top-1000.
__global__ __launch_bounds__(1024) void k_sort(
    const ull* __restrict__ ckeys, const int* __restrict__ ctotal,
    float* __restrict__ topk_score, int* __restrict__ topk_idx) {
  __shared__ ull skeys[SORTN];
  int b = blockIdx.x, tid = threadIdx.x;
  int total = min(ctotal[b], SORTN);
  for (int i = tid; i < SORTN; i += 1024)
    skeys[i] = (i < total) ? ckeys[(size_t)b * SORTN + i] : 0ull;
  __syncthreads();
  for (int k = 2; k <= SORTN; k <<= 1) {
    for (int j = k >> 1; j > 0; j >>= 1) {
      for (int t = tid; t < SORTN; t += 1024) {
        int ixj = t ^ j;
        if (ixj > t) {
          ull a = skeys[t], c2 = skeys[ixj];
          bool up = ((t & k) == 0);
          bool sw = up ? (a < c2) : (a > c2);
          if (sw) { skeys[t] = c2; skeys[ixj] = a; }
        }
      }
      __syncthreads();
    }
  }
  int valid_n = min(total, KTOP);
  if (tid < KTOP) {
    if (tid < valid_n) {
      ull key = skeys[tid];
      topk_score[b * KTOP + tid] = __uint_as_float((unsigned)(key >> 32));
      topk_idx[b * KTOP + tid] = (int)(~(unsigned)key);
    } else {
      topk_score[b * KTOP + tid] = NEGV;
      topk_idx[b * KTOP + tid] = -1;
    }
  }
}

__global__ __launch_bounds__(256) void k_decode(
    const float* __restrict__ boxreg, const float* __restrict__ props,
    const int* __restrict__ hw, const int* __restrict__ topk_idx,
    float* __restrict__ det_box, int* __restrict__ det_label,
    int* __restrict__ det_valid) {
  int g = blockIdx.x * 256 + threadIdx.x;
  if (g >= NB * KTOP) return;
  int b = g / KTOP;
  int fidx = topk_idx[g];
  if (fidx < 0) {
    det_box[(size_t)g * 4 + 0] = 0.0f;
    det_box[(size_t)g * 4 + 1] = 0.0f;
    det_box[(size_t)g * 4 + 2] = 0.0f;
    det_box[(size_t)g * 4 + 3] = 0.0f;
    det_label[g] = 0;
    det_valid[g] = 0;
    return;
  }
  int p = fidx / (NC - 1), c = fidx % (NC - 1) + 1;
  float Hf = (float)hw[0], Wf = (float)hw[1];
  float4 pr = reinterpret_cast<const float4*>(props)[b * NP + p];
  float4 rel =
      reinterpret_cast<const float4*>(boxreg + (size_t)(b * NP + p) * 4 * NC)[c];
  float x1, y1, x2, y2;
  decode_box(pr, rel, Wf, Hf, x1, y1, x2, y2);
  det_box[(size_t)g * 4 + 0] = x1;
  det_box[(size_t)g * 4 + 1] = y1;
  det_box[(size_t)g * 4 + 2] = x2;
  det_box[(size_t)g * 4 + 3] = y2;
  det_label[g] = c;
  det_valid[g] = 1;
}

// Suppression bit-matrix (labels-equal == class-offset NMS exactly, since
// offset_scale=1334 > max coord 1333 makes cross-class IoU 0).
__global__ __launch_bounds__(256) void k_mask(
    const float* __restrict__ det_box, const int* __restrict__ det_label,
    ull* __restrict__ maskmat) {
  int g = blockIdx.x * 256 + threadIdx.x;
  if (g >= NB * KTOP * 16) return;
  int w = g & 15;
  int i = (g >> 4) % KTOP;
  int b = (g >> 4) / KTOP;
  const float4* bb = reinterpret_cast<const float4*>(det_box) + (size_t)b * KTOP;
  const int* ll = det_label + b * KTOP;
  float4 bi = bb[i];
  int li = ll[i];
  float areai = (bi.z - bi.x) * (bi.w - bi.y);
  ull bits = 0;
  int j0 = w * 64;
  for (int t = 0; t < 64; ++t) {
    int j = j0 + t;
    if (j > i && j < KTOP && ll[j] == li) {
      float4 bj = bb[j];
      float areaj = (bj.z - bj.x) * (bj.w - bj.y);
      float ltx = fmaxf(bi.x, bj.x), lty = fmaxf(bi.y, bj.y);
      float rbx = fminf(bi.z, bj.z), rby = fminf(bi.w, bj.w);
      float iw = fmaxf(rbx - ltx, 0.0f), ih = fmaxf(rby - lty, 0.0f);
      float inter = iw * ih;
      float iou = inter / (areai + areaj - inter + 1e-9f);
      if (iou > NMS_T) bits |= (1ull << t);
    }
  }
  maskmat[((size_t)b * MROWS + i) * 16 + w] = bits;
}

// Windowed greedy NMS: 16 windows of 64 rows. Per window: transpose the 64x64
// intra block across lanes (6 shfl_xor stages), resolve 64 decisions with a
// register-only ballot loop, then OR kept rows' masks into 4-way-partial supp
// (all 64 lanes: group g = lane>>4 handles 16 rows, word = lane&15).
__global__ __launch_bounds__(64) void k_greedy(
    const ull* __restrict__ maskmat, const int* __restrict__ det_valid,
    int* __restrict__ keep) {
  int b = blockIdx.x;
  int lane = threadIdx.x;
  int wl = lane & 15;
  int grp = lane >> 4;
  // validw: lane w (w<16) holds valid bits for rows w*64..w*64+63
  ull validw = 0;
#pragma unroll
  for (int w = 0; w < 16; ++w) {
    int j = w * 64 + lane;
    int f = (j < KTOP) ? det_valid[b * KTOP + j] : 0;
    ull m = __ballot(f != 0);
    if (lane == w) validw = m;
  }
  // supp partials: lane l holds group (l>>4) partial of word (l&15).
  // true word w = OR of partials in lanes {w, w+16, w+32, w+48}.
  ull supp = (lane < 16) ? ~validw : 0ull;  // invalid == pre-suppressed
  const ull* mrow = maskmat + (size_t)b * MROWS * 16;

  for (int w = 0; w < 16; ++w) {
    int t0 = w * 64;
    int row = t0 + lane;
    // intra word: row's columns t0..t0+63 (padding rows read garbage, masked by K)
    ull r = mrow[(size_t)row * 16 + w];
    if (row >= KTOP) r = 0ull;
    // transpose 64x64 bit block: after, bit i of lane l = M[t0+i][t0+l]
#pragma unroll
    for (int dd = 0; dd < 6; ++dd) {
      const int d = 1 << dd;
      const ull M0 = (dd == 0) ? 0x5555555555555555ull
                   : (dd == 1) ? 0x3333333333333333ull
                   : (dd == 2) ? 0x0F0F0F0F0F0F0F0Full
                   : (dd == 3) ? 0x00FF00FF00FF00FFull
                   : (dd == 4) ? 0x0000FFFF0000FFFFull
                               : 0x00000000FFFFFFFFull;
      ull y = shfl_xor64(r, d);
      r = ((lane & d) == 0) ? ((r & M0) | ((y & M0) << d))
                            : ((r & ~M0) | ((y >> d) & M0));
    }
    // incoming suppression word for this window (OR of 4 partials)
    ull inc = shfl64(supp, w) | shfl64(supp, w + 16) |
              shfl64(supp, w + 32) | shfl64(supp, w + 48);
    unsigned s32 = (unsigned)((inc >> lane) & 1ull);
    // serial in-window resolution: register-only chain
#pragma unroll
    for (int i = 0; i < 64; ++i) {
      ull act = __ballot(s32 == 0);   // only bit i is final; that's all we read
      s32 |= (unsigned)(((act & r) >> i) & 1ull);
    }
    ull K = __ballot(s32 == 0);       // kept rows of this window (uniform)
    if (row < KTOP) keep[b * KTOP + row] = (s32 == 0) ? 1 : 0;
    // cross-window update: OR kept rows' mask words into supp partials
    ull acc = 0;
    int base_r = grp * 16;
#pragma unroll
    for (int k = 0; k < 16; ++k) {
      int i = base_r + k;
      ull v = mrow[(size_t)(t0 + i) * 16 + wl];  // padded rows in-bounds; masked below
      if ((K >> i) & 1ull) acc |= v;
    }
    supp |= acc;
  }
}

// First 100 kept (in sorted order) -> outputs, zero-pad the rest.
__global__ __launch_bounds__(256) void k_output(
    const float* __restrict__ topk_score, const float* __restrict__ det_box,
    const int* __restrict__ det_label, const int* __restrict__ keep,
    float* __restrict__ out) {
  int b = blockIdx.x, tid = threadIdx.x;
  __shared__ int pf[1024];
  for (int i = tid; i < 1024; i += 256) pf[i] = (i < KTOP) ? keep[b * KTOP + i] : 0;
  __syncthreads();
  for (int d = 1; d < 1024; d <<= 1) {
    int v[4];
#pragma unroll
    for (int k = 0; k < 4; ++k) {
      int i = tid + k * 256;
      v[k] = pf[i] + ((i >= d) ? pf[i - d] : 0);
    }
    __syncthreads();
#pragma unroll
    for (int k = 0; k < 4; ++k) pf[tid + k * 256] = v[k];
    __syncthreads();
  }
  int total = min(pf[KTOP - 1], NDET);
  float* ob = out;
  float* os = out + (size_t)NB * NDET * 4;
  float* ol = os + (size_t)NB * NDET;
  for (int i = tid; i < KTOP; i += 256) {
    if (keep[b * KTOP + i]) {
      int r = pf[i] - 1;
      if (r < NDET) {
        ob[((size_t)b * NDET + r) * 4 + 0] = det_box[((size_t)b * KTOP + i) * 4 + 0];
        ob[((size_t)b * NDET + r) * 4 + 1] = det_box[((size_t)b * KTOP + i) * 4 + 1];
        ob[((size_t)b * NDET + r) * 4 + 2] = det_box[((size_t)b * KTOP + i) * 4 + 2];
        ob[((size_t)b * NDET + r) * 4 + 3] = det_box[((size_t)b * KTOP + i) * 4 + 3];
        os[b * NDET + r] = topk_score[b * KTOP + i];
        ol[b * NDET + r] = (float)det_label[b * KTOP + i];
      }
    }
  }
  for (int r = total + tid; r < NDET; r += 256) {
    ob[((size_t)b * NDET + r) * 4 + 0] = 0.0f;
    ob[((size_t)b * NDET + r) * 4 + 1] = 0.0f;
    ob[((size_t)b * NDET + r) * 4 + 2] = 0.0f;
    ob[((size_t)b * NDET + r) * 4 + 3] = 0.0f;
    os[b * NDET + r] = 0.0f;
    ol[b * NDET + r] = 0.0f;
  }
}

}  // namespace

extern "C" void kernel_launch(void* const* d_in, const int* in_sizes, int n_in,
                              void* d_out, int out_size, void* d_ws, size_t ws_size,
                              hipStream_t stream) {
  const float* logits = (const float*)d_in[0];
  const float* boxreg = (const float*)d_in[1];
  const float* props = (const float*)d_in[2];
  const int* hw = (const int*)d_in[3];

  char* ws = (char*)d_ws;
  size_t off = 0;
  auto alloc = [&](size_t bytes) -> void* {
    void* p = ws + off;
    off += (bytes + 255) & ~(size_t)255;
    return p;
  };
  ull* keys = (ull*)alloc((size_t)NB * NP * SLOTS * 8);
  int* pcount = (int*)alloc((size_t)NB * NP * 4);
  int* ghist = (int*)alloc((size_t)NB * NBUCK * 4);
  int* ccur = (int*)alloc((size_t)NB * NBUCK * 4);
  int* sboundA = (int*)alloc(NB * 4);
  int* ctotal = (int*)alloc(NB * 4);
  ull* ckeys = (ull*)alloc((size_t)NB * SORTN * 8);
  float* topk_score = (float*)alloc((size_t)NB * KTOP * 4);
  int* topk_idx = (int*)alloc((size_t)NB * KTOP * 4);
  float* det_box = (float*)alloc((size_t)NB * KTOP * 16);
  int* det_label = (int*)alloc((size_t)NB * KTOP * 4);
  int* det_valid = (int*)alloc((size_t)NB * KTOP * 4);
  ull* maskmat = (ull*)alloc((size_t)NB * MROWS * 16 * 8);
  int* keep = (int*)alloc((size_t)NB * KTOP * 4);

  k_zero<<<(NB * NBUCK + 255) / 256, 256, 0, stream>>>(ghist);
  k_candidates<<<(NB * NP) / 4, 256, 0, stream>>>(logits, boxreg, props, hw,
                                                  keys, pcount, ghist);
  k_bound<<<NB, 1024, 0, stream>>>(ghist, ccur, sboundA, ctotal);
  k_compact<<<(NB * NP * SLOTS) / 256, 256, 0, stream>>>(keys, pcount, sboundA, ccur, ckeys);
  k_sort<<<NB, 1024, 0, stream>>>(ckeys, ctotal, topk_score, topk_idx);
  k_decode<<<(NB * KTOP + 255) / 256, 256, 0, stream>>>(boxreg, props, hw, topk_idx,
                                                        det_box, det_label, det_valid);
  k_mask<<<(NB * KTOP * 16 + 255) / 256, 256, 0, stream>>>(det_box, det_label, maskmat);
  k_greedy<<<NB, 64, 0, stream>>>(maskmat, det_valid, keep);
  k_output<<<NB, 256, 0, stream>>>(topk_score, det_box, det_label, keep, (float*)d_out);
}